// Round 1
// baseline (1670.825 us; speedup 1.0000x reference)
//
#include <hip/hip_runtime.h>

#define N_NODES 100000
#define N_EDGES 1600000
#define HDIM    64
#define NLAYERS 5
#define NGRAPH  128
#define NOUT    10
#define BN_EPS  1e-5f

static __device__ __forceinline__ float bcastf(float v, int l) {
    return __int_as_float(__builtin_amdgcn_readlane(__float_as_int(v), l));
}

// ---------------- CSR build ----------------

__global__ __launch_bounds__(256) void k_hist(const int* __restrict__ dst, int* __restrict__ counts) {
    int e = blockIdx.x * 256 + threadIdx.x;
    if (e < N_EDGES) atomicAdd(&counts[dst[e]], 1);
}

__global__ __launch_bounds__(256) void k_scan_bt(const int* __restrict__ counts, int* __restrict__ bsums) {
    __shared__ int sm[256];
    int t = threadIdx.x;
    int base = blockIdx.x * 1024 + t * 4;
    int s = 0;
#pragma unroll
    for (int k = 0; k < 4; ++k) { int i = base + k; s += (i < N_NODES) ? counts[i] : 0; }
    sm[t] = s; __syncthreads();
    for (int o = 128; o > 0; o >>= 1) { if (t < o) sm[t] += sm[t + o]; __syncthreads(); }
    if (t == 0) bsums[blockIdx.x] = sm[0];
}

__global__ void k_scan_tot(int* bsums, int nblk, int* offsets) {
    if (threadIdx.x == 0 && blockIdx.x == 0) {
        int run = 0;
        for (int i = 0; i < nblk; ++i) { int v = bsums[i]; bsums[i] = run; run += v; }
        offsets[N_NODES] = N_EDGES;
    }
}

__global__ __launch_bounds__(256) void k_scan_fin(const int* __restrict__ counts, const int* __restrict__ bsums,
                                                 int* __restrict__ offsets, int* __restrict__ cursor) {
    __shared__ int sm[256];
    int t = threadIdx.x;
    int base = blockIdx.x * 1024 + t * 4;
    int v[4]; int s = 0;
#pragma unroll
    for (int k = 0; k < 4; ++k) { int i = base + k; v[k] = (i < N_NODES) ? counts[i] : 0; s += v[k]; }
    sm[t] = s; __syncthreads();
    for (int o = 1; o < 256; o <<= 1) {
        int add = (t >= o) ? sm[t - o] : 0;
        __syncthreads();
        sm[t] += add;
        __syncthreads();
    }
    int run = bsums[blockIdx.x] + (sm[t] - s);
#pragma unroll
    for (int k = 0; k < 4; ++k) {
        int i = base + k;
        if (i < N_NODES) { offsets[i] = run; cursor[i] = run; run += v[k]; }
    }
}

__global__ __launch_bounds__(256) void k_fill(const int* __restrict__ src, const int* __restrict__ dst,
                                              int* __restrict__ cursor, int* __restrict__ csr) {
    int e = blockIdx.x * 256 + threadIdx.x;
    if (e < N_EDGES) {
        int d = dst[e];
        int p = atomicAdd(&cursor[d], 1);
        csr[p] = src[e];
    }
}

// ---------------- per-layer kernels ----------------

// 16 lanes per node, float4 per lane: agg[n] = sum over in-edges of x[src]
__global__ __launch_bounds__(256) void k_agg(const float4* __restrict__ x4, const int* __restrict__ offsets,
                                             const int* __restrict__ csr, float4* __restrict__ agg4) {
    int tid = blockIdx.x * 256 + threadIdx.x;
    int n = tid >> 4, q = tid & 15;
    if (n >= N_NODES) return;
    int beg = offsets[n], end = offsets[n + 1];
    float4 a = make_float4(0.f, 0.f, 0.f, 0.f);
    for (int e = beg; e < end; ++e) {
        int s = csr[e];
        float4 v = x4[s * 16 + q];
        a.x += v.x; a.y += v.y; a.z += v.z; a.w += v.w;
    }
    agg4[n * 16 + q] = a;
}

// lane = output feature; W columns held in registers; input broadcast via readlane.
// Reads x + agg, writes h2 in-place over agg, accumulates BN sum/sumsq.
__global__ __launch_bounds__(256) void k_mlp(const float* __restrict__ x, float* __restrict__ aggh2,
                                             const float* __restrict__ W1, const float* __restrict__ b1,
                                             const float* __restrict__ W2, const float* __restrict__ b2,
                                             float* __restrict__ stats) {
    int lane = threadIdx.x & 63;
    int wave = (blockIdx.x * blockDim.x + threadIdx.x) >> 6;
    int nwaves = (gridDim.x * blockDim.x) >> 6;
    float w1r[64], w2r[64];
#pragma unroll
    for (int k = 0; k < 64; ++k) {
        w1r[k] = W1[k * 64 + lane];
        w2r[k] = W2[k * 64 + lane];
    }
    float b1r = b1[lane], b2r = b2[lane];
    float lsum = 0.f, lsq = 0.f;
    for (int n = wave; n < N_NODES; n += nwaves) {
        float inj = x[n * 64 + lane] + aggh2[n * 64 + lane];
        float acc = b1r;
#pragma unroll
        for (int k = 0; k < 64; ++k) acc = fmaf(bcastf(inj, k), w1r[k], acc);
        float h1 = fmaxf(acc, 0.f);
        float acc2 = b2r;
#pragma unroll
        for (int k = 0; k < 64; ++k) acc2 = fmaf(bcastf(h1, k), w2r[k], acc2);
        aggh2[n * 64 + lane] = acc2;
        lsum += acc2; lsq += acc2 * acc2;
    }
    atomicAdd(&stats[lane], lsum);
    atomicAdd(&stats[64 + lane], lsq);
}

__global__ __launch_bounds__(256) void k_bn(const float4* __restrict__ h2, const float* __restrict__ stats,
                                            const float* __restrict__ gam, const float* __restrict__ bet,
                                            float4* __restrict__ xout) {
    int tid = blockIdx.x * 256 + threadIdx.x;
    if (tid >= N_NODES * 16) return;
    int j0 = (tid & 15) * 4;
    const float invN = 1.0f / (float)N_NODES;
    float sc[4], sh[4];
#pragma unroll
    for (int c = 0; c < 4; ++c) {
        int j = j0 + c;
        float mean = stats[j] * invN;
        float var = stats[64 + j] * invN - mean * mean;
        float s = gam[j] * rsqrtf(var + BN_EPS);
        sc[c] = s; sh[c] = bet[j] - mean * s;
    }
    float4 v = h2[tid];
    v.x = fmaxf(fmaf(v.x, sc[0], sh[0]), 0.f);
    v.y = fmaxf(fmaf(v.y, sc[1], sh[1]), 0.f);
    v.z = fmaxf(fmaf(v.z, sc[2], sh[2]), 0.f);
    v.w = fmaxf(fmaf(v.w, sc[3], sh[3]), 0.f);
    xout[tid] = v;
}

// ---------------- pooling + head ----------------

__global__ __launch_bounds__(256) void k_pool(const float* __restrict__ x, const int* __restrict__ b,
                                              float* __restrict__ pooled) {
    int tid = blockIdx.x * 256 + threadIdx.x;
    if (tid < N_NODES * 64) {
        int n = tid >> 6, j = tid & 63;
        atomicAdd(&pooled[b[n] * 64 + j], x[tid]);
    }
}

__global__ __launch_bounds__(256) void k_cnt(const int* __restrict__ b, float* __restrict__ cnts) {
    int n = blockIdx.x * 256 + threadIdx.x;
    if (n < N_NODES) atomicAdd(&cnts[b[n]], 1.0f);
}

__global__ __launch_bounds__(128) void k_head(const float* __restrict__ pooled, const float* __restrict__ cnts,
                                              const float* __restrict__ W1, const float* __restrict__ b1,
                                              const float* __restrict__ W2, const float* __restrict__ b2,
                                              float* __restrict__ out) {
    __shared__ float w1s[64 * 64];
    __shared__ float w2s[64 * NOUT];
    int t = threadIdx.x;
    for (int i = t; i < 64 * 64; i += 128) w1s[i] = W1[i];
    for (int i = t; i < 64 * NOUT; i += 128) w2s[i] = W2[i];
    __syncthreads();
    int g = t;  // 128 threads == NGRAPH
    float inv = 1.0f / fmaxf(cnts[g], 1.0f);
    float pr[64];
#pragma unroll
    for (int k = 0; k < 64; ++k) pr[k] = pooled[g * 64 + k] * inv;
    float acc[NOUT];
#pragma unroll
    for (int o = 0; o < NOUT; ++o) acc[o] = b2[o];
    for (int j = 0; j < 64; ++j) {
        float h = b1[j];
#pragma unroll
        for (int k = 0; k < 64; ++k) h = fmaf(pr[k], w1s[k * 64 + j], h);
        h = fmaxf(h, 0.f);
#pragma unroll
        for (int o = 0; o < NOUT; ++o) acc[o] = fmaf(h, w2s[j * NOUT + o], acc[o]);
    }
#pragma unroll
    for (int o = 0; o < NOUT; ++o) out[g * NOUT + o] = acc[o];
}

// ---------------- launch ----------------

extern "C" void kernel_launch(void* const* d_in, const int* in_sizes, int n_in,
                              void* d_out, int out_size, void* d_ws, size_t ws_size,
                              hipStream_t stream) {
    const float* x0  = (const float*)d_in[0];
    const int*   ei  = (const int*)d_in[1];
    const int*   b   = (const int*)d_in[2];
    const float* cW1 = (const float*)d_in[3];
    const float* cb1 = (const float*)d_in[4];
    const float* cW2 = (const float*)d_in[5];
    const float* cb2 = (const float*)d_in[6];
    const float* gam = (const float*)d_in[7];
    const float* bet = (const float*)d_in[8];
    const float* hW1 = (const float*)d_in[9];
    const float* hb1 = (const float*)d_in[10];
    const float* hW2 = (const float*)d_in[11];
    const float* hb2 = (const float*)d_in[12];
    float* out = (float*)d_out;

    char* ws = (char*)d_ws;
    size_t off = 0;
    auto alloc = [&](size_t bytes) { void* p = ws + off; off += (bytes + 255) & ~(size_t)255; return p; };
    float* agg    = (float*)alloc((size_t)N_NODES * 64 * sizeof(float));   // doubles as h2
    float* xbuf   = (float*)alloc((size_t)N_NODES * 64 * sizeof(float));
    int*   csr    = (int*)alloc((size_t)N_EDGES * sizeof(int));
    int*   counts = (int*)alloc((size_t)(N_NODES + 1) * sizeof(int));
    int*   offs   = (int*)alloc((size_t)(N_NODES + 1) * sizeof(int));
    int*   cursor = (int*)alloc((size_t)(N_NODES + 1) * sizeof(int));
    int*   bsums  = (int*)alloc(256 * sizeof(int));
    float* stats  = (float*)alloc(NLAYERS * 128 * sizeof(float));
    float* pooled = (float*)alloc(NGRAPH * 64 * sizeof(float));
    float* cnts   = (float*)alloc(NGRAPH * sizeof(float));

    const int* src = ei;
    const int* dst = ei + N_EDGES;

    hipMemsetAsync(counts, 0, (N_NODES + 1) * sizeof(int), stream);
    hipMemsetAsync(stats, 0, NLAYERS * 128 * sizeof(float), stream);
    hipMemsetAsync(pooled, 0, NGRAPH * 64 * sizeof(float), stream);
    hipMemsetAsync(cnts, 0, NGRAPH * sizeof(float), stream);

    const int EB = (N_EDGES + 255) / 256;            // 6250
    const int SB = (N_NODES + 1023) / 1024;          // 98
    k_hist<<<EB, 256, 0, stream>>>(dst, counts);
    k_scan_bt<<<SB, 256, 0, stream>>>(counts, bsums);
    k_scan_tot<<<1, 1, 0, stream>>>(bsums, SB, offs);
    k_scan_fin<<<SB, 256, 0, stream>>>(counts, bsums, offs, cursor);
    k_fill<<<EB, 256, 0, stream>>>(src, dst, cursor, csr);

    const int AB = (N_NODES * 16 + 255) / 256;       // 6250
    const float* xc = x0;
    for (int l = 0; l < NLAYERS; ++l) {
        k_agg<<<AB, 256, 0, stream>>>((const float4*)xc, offs, csr, (float4*)agg);
        k_mlp<<<1024, 256, 0, stream>>>(xc, agg,
                                        cW1 + (size_t)l * 64 * 64, cb1 + l * 64,
                                        cW2 + (size_t)l * 64 * 64, cb2 + l * 64,
                                        stats + l * 128);
        k_bn<<<AB, 256, 0, stream>>>((const float4*)agg, stats + l * 128,
                                     gam + l * 64, bet + l * 64, (float4*)xbuf);
        xc = xbuf;
    }

    k_pool<<<(N_NODES * 64 + 255) / 256, 256, 0, stream>>>(xc, b, pooled);
    k_cnt<<<(N_NODES + 255) / 256, 256, 0, stream>>>(b, cnts);
    k_head<<<1, 128, 0, stream>>>(pooled, cnts, hW1, hb1, hW2, hb2, out);
}

// Round 2
// 1250.026 us; speedup vs baseline: 1.3366x; 1.3366x over previous
//
#include <hip/hip_runtime.h>

#define N_NODES 100000
#define N_EDGES 1600000
#define HDIM    64
#define NLAYERS 5
#define NGRAPH  128
#define NOUT    10
#define BN_EPS  1e-5f

static __device__ __forceinline__ float bcastf(float v, int l) {
    return __int_as_float(__builtin_amdgcn_readlane(__float_as_int(v), l));
}

// ---------------- CSR build ----------------

__global__ __launch_bounds__(256) void k_hist(const int* __restrict__ dst, int* __restrict__ counts) {
    int e = blockIdx.x * 256 + threadIdx.x;
    if (e < N_EDGES) atomicAdd(&counts[dst[e]], 1);
}

__global__ __launch_bounds__(256) void k_scan_bt(const int* __restrict__ counts, int* __restrict__ bsums) {
    __shared__ int sm[256];
    int t = threadIdx.x;
    int base = blockIdx.x * 1024 + t * 4;
    int s = 0;
#pragma unroll
    for (int k = 0; k < 4; ++k) { int i = base + k; s += (i < N_NODES) ? counts[i] : 0; }
    sm[t] = s; __syncthreads();
    for (int o = 128; o > 0; o >>= 1) { if (t < o) sm[t] += sm[t + o]; __syncthreads(); }
    if (t == 0) bsums[blockIdx.x] = sm[0];
}

__global__ void k_scan_tot(int* bsums, int nblk, int* offsets) {
    if (threadIdx.x == 0 && blockIdx.x == 0) {
        int run = 0;
        for (int i = 0; i < nblk; ++i) { int v = bsums[i]; bsums[i] = run; run += v; }
        offsets[N_NODES] = N_EDGES;
    }
}

__global__ __launch_bounds__(256) void k_scan_fin(const int* __restrict__ counts, const int* __restrict__ bsums,
                                                 int* __restrict__ offsets, int* __restrict__ cursor) {
    __shared__ int sm[256];
    int t = threadIdx.x;
    int base = blockIdx.x * 1024 + t * 4;
    int v[4]; int s = 0;
#pragma unroll
    for (int k = 0; k < 4; ++k) { int i = base + k; v[k] = (i < N_NODES) ? counts[i] : 0; s += v[k]; }
    sm[t] = s; __syncthreads();
    for (int o = 1; o < 256; o <<= 1) {
        int add = (t >= o) ? sm[t - o] : 0;
        __syncthreads();
        sm[t] += add;
        __syncthreads();
    }
    int run = bsums[blockIdx.x] + (sm[t] - s);
#pragma unroll
    for (int k = 0; k < 4; ++k) {
        int i = base + k;
        if (i < N_NODES) { offsets[i] = run; cursor[i] = run; run += v[k]; }
    }
}

__global__ __launch_bounds__(256) void k_fill(const int* __restrict__ src, const int* __restrict__ dst,
                                              int* __restrict__ cursor, int* __restrict__ csr) {
    int e = blockIdx.x * 256 + threadIdx.x;
    if (e < N_EDGES) {
        int d = dst[e];
        int p = atomicAdd(&cursor[d], 1);
        csr[p] = src[e];
    }
}

// ---------------- per-layer kernels ----------------

// 16 lanes per node, float4 per lane: agg[n] = sum over in-edges of x[src]
__global__ __launch_bounds__(256) void k_agg(const float4* __restrict__ x4, const int* __restrict__ offsets,
                                             const int* __restrict__ csr, float4* __restrict__ agg4) {
    int tid = blockIdx.x * 256 + threadIdx.x;
    int n = tid >> 4, q = tid & 15;
    if (n >= N_NODES) return;
    int beg = offsets[n], end = offsets[n + 1];
    float4 a = make_float4(0.f, 0.f, 0.f, 0.f);
    for (int e = beg; e < end; ++e) {
        int s = csr[e];
        float4 v = x4[s * 16 + q];
        a.x += v.x; a.y += v.y; a.z += v.z; a.w += v.w;
    }
    agg4[n * 16 + q] = a;
}

// lane = output feature; W columns held in registers; input broadcast via readlane.
// Reads x + agg, writes h2 in-place over agg, accumulates BN sum/sumsq.
__global__ __launch_bounds__(256) void k_mlp(const float* __restrict__ x, float* __restrict__ aggh2,
                                             const float* __restrict__ W1, const float* __restrict__ b1,
                                             const float* __restrict__ W2, const float* __restrict__ b2,
                                             float* __restrict__ stats) {
    int lane = threadIdx.x & 63;
    int wave = (blockIdx.x * blockDim.x + threadIdx.x) >> 6;
    int nwaves = (gridDim.x * blockDim.x) >> 6;
    float w1r[64], w2r[64];
#pragma unroll
    for (int k = 0; k < 64; ++k) {
        w1r[k] = W1[k * 64 + lane];
        w2r[k] = W2[k * 64 + lane];
    }
    float b1r = b1[lane], b2r = b2[lane];
    float lsum = 0.f, lsq = 0.f;
    for (int n = wave; n < N_NODES; n += nwaves) {
        float inj = x[n * 64 + lane] + aggh2[n * 64 + lane];
        float acc = b1r;
#pragma unroll
        for (int k = 0; k < 64; ++k) acc = fmaf(bcastf(inj, k), w1r[k], acc);
        float h1 = fmaxf(acc, 0.f);
        float acc2 = b2r;
#pragma unroll
        for (int k = 0; k < 64; ++k) acc2 = fmaf(bcastf(h1, k), w2r[k], acc2);
        aggh2[n * 64 + lane] = acc2;
        lsum += acc2; lsq += acc2 * acc2;
    }
    atomicAdd(&stats[lane], lsum);
    atomicAdd(&stats[64 + lane], lsq);
}

__global__ __launch_bounds__(256) void k_bn(const float4* __restrict__ h2, const float* __restrict__ stats,
                                            const float* __restrict__ gam, const float* __restrict__ bet,
                                            float4* __restrict__ xout) {
    int tid = blockIdx.x * 256 + threadIdx.x;
    if (tid >= N_NODES * 16) return;
    int j0 = (tid & 15) * 4;
    const float invN = 1.0f / (float)N_NODES;
    float sc[4], sh[4];
#pragma unroll
    for (int c = 0; c < 4; ++c) {
        int j = j0 + c;
        float mean = stats[j] * invN;
        float var = stats[64 + j] * invN - mean * mean;
        float s = gam[j] * rsqrtf(var + BN_EPS);
        sc[c] = s; sh[c] = bet[j] - mean * s;
    }
    float4 v = h2[tid];
    v.x = fmaxf(fmaf(v.x, sc[0], sh[0]), 0.f);
    v.y = fmaxf(fmaf(v.y, sc[1], sh[1]), 0.f);
    v.z = fmaxf(fmaf(v.z, sc[2], sh[2]), 0.f);
    v.w = fmaxf(fmaf(v.w, sc[3], sh[3]), 0.f);
    xout[tid] = v;
}

// ---------------- pooling + head (b is sorted -> segment boundaries) ----------------

__global__ void k_bounds(const int* __restrict__ b, int* __restrict__ bounds) {
    int g = threadIdx.x;           // 0..NGRAPH inclusive
    if (g > NGRAPH) return;
    int lo = 0, hi = N_NODES;      // first i with b[i] >= g
    while (lo < hi) { int mid = (lo + hi) >> 1; if (b[mid] < g) lo = mid + 1; else hi = mid; }
    bounds[g] = lo;
}

// one block per graph: segmented mean, no atomics
__global__ __launch_bounds__(256) void k_pool(const float4* __restrict__ x4, const int* __restrict__ bounds,
                                              float4* __restrict__ pooled4) {
    int g = blockIdx.x;
    int beg = bounds[g], end = bounds[g + 1];
    int t = threadIdx.x;
    int q = t & 15;        // float4 slot within row
    int w = t >> 4;        // 16 node-walkers
    float4 a = make_float4(0.f, 0.f, 0.f, 0.f);
    for (int n = beg + w; n < end; n += 16) {
        float4 v = x4[n * 16 + q];
        a.x += v.x; a.y += v.y; a.z += v.z; a.w += v.w;
    }
    __shared__ float4 sm[16][16];
    sm[w][q] = a; __syncthreads();
    for (int o = 8; o > 0; o >>= 1) {
        if (w < o) {
            float4 u = sm[w + o][q];
            sm[w][q].x += u.x; sm[w][q].y += u.y; sm[w][q].z += u.z; sm[w][q].w += u.w;
        }
        __syncthreads();
    }
    if (w == 0) {
        float inv = (end > beg) ? 1.0f / (float)(end - beg) : 0.0f;
        float4 r = sm[0][q];
        r.x *= inv; r.y *= inv; r.z *= inv; r.w *= inv;
        pooled4[g * 16 + q] = r;
    }
}

__global__ __launch_bounds__(128) void k_head(const float* __restrict__ pooled,
                                              const float* __restrict__ W1, const float* __restrict__ b1,
                                              const float* __restrict__ W2, const float* __restrict__ b2,
                                              float* __restrict__ out) {
    __shared__ float w1s[64 * 64];
    __shared__ float w2s[64 * NOUT];
    int t = threadIdx.x;
    for (int i = t; i < 64 * 64; i += 128) w1s[i] = W1[i];
    for (int i = t; i < 64 * NOUT; i += 128) w2s[i] = W2[i];
    __syncthreads();
    int g = t;  // 128 threads == NGRAPH
    float pr[64];
#pragma unroll
    for (int k = 0; k < 64; ++k) pr[k] = pooled[g * 64 + k];
    float acc[NOUT];
#pragma unroll
    for (int o = 0; o < NOUT; ++o) acc[o] = b2[o];
    for (int j = 0; j < 64; ++j) {
        float h = b1[j];
#pragma unroll
        for (int k = 0; k < 64; ++k) h = fmaf(pr[k], w1s[k * 64 + j], h);
        h = fmaxf(h, 0.f);
#pragma unroll
        for (int o = 0; o < NOUT; ++o) acc[o] = fmaf(h, w2s[j * NOUT + o], acc[o]);
    }
#pragma unroll
    for (int o = 0; o < NOUT; ++o) out[g * NOUT + o] = acc[o];
}

// ---------------- launch ----------------

extern "C" void kernel_launch(void* const* d_in, const int* in_sizes, int n_in,
                              void* d_out, int out_size, void* d_ws, size_t ws_size,
                              hipStream_t stream) {
    const float* x0  = (const float*)d_in[0];
    const int*   ei  = (const int*)d_in[1];
    const int*   b   = (const int*)d_in[2];
    const float* cW1 = (const float*)d_in[3];
    const float* cb1 = (const float*)d_in[4];
    const float* cW2 = (const float*)d_in[5];
    const float* cb2 = (const float*)d_in[6];
    const float* gam = (const float*)d_in[7];
    const float* bet = (const float*)d_in[8];
    const float* hW1 = (const float*)d_in[9];
    const float* hb1 = (const float*)d_in[10];
    const float* hW2 = (const float*)d_in[11];
    const float* hb2 = (const float*)d_in[12];
    float* out = (float*)d_out;

    char* ws = (char*)d_ws;
    size_t off = 0;
    auto alloc = [&](size_t bytes) { void* p = ws + off; off += (bytes + 255) & ~(size_t)255; return p; };
    float* agg    = (float*)alloc((size_t)N_NODES * 64 * sizeof(float));   // doubles as h2
    float* xbuf   = (float*)alloc((size_t)N_NODES * 64 * sizeof(float));
    int*   csr    = (int*)alloc((size_t)N_EDGES * sizeof(int));
    int*   counts = (int*)alloc((size_t)(N_NODES + 1) * sizeof(int));
    int*   offs   = (int*)alloc((size_t)(N_NODES + 1) * sizeof(int));
    int*   cursor = (int*)alloc((size_t)(N_NODES + 1) * sizeof(int));
    int*   bsums  = (int*)alloc(256 * sizeof(int));
    float* stats  = (float*)alloc(NLAYERS * 128 * sizeof(float));
    float* pooled = (float*)alloc(NGRAPH * 64 * sizeof(float));
    int*   bounds = (int*)alloc((NGRAPH + 1) * sizeof(int));

    const int* src = ei;
    const int* dst = ei + N_EDGES;

    hipMemsetAsync(counts, 0, (N_NODES + 1) * sizeof(int), stream);
    hipMemsetAsync(stats, 0, NLAYERS * 128 * sizeof(float), stream);

    const int EB = (N_EDGES + 255) / 256;            // 6250
    const int SB = (N_NODES + 1023) / 1024;          // 98
    k_hist<<<EB, 256, 0, stream>>>(dst, counts);
    k_scan_bt<<<SB, 256, 0, stream>>>(counts, bsums);
    k_scan_tot<<<1, 1, 0, stream>>>(bsums, SB, offs);
    k_scan_fin<<<SB, 256, 0, stream>>>(counts, bsums, offs, cursor);
    k_fill<<<EB, 256, 0, stream>>>(src, dst, cursor, csr);
    k_bounds<<<1, NGRAPH + 1, 0, stream>>>(b, bounds);

    const int AB = (N_NODES * 16 + 255) / 256;       // 6250
    const float* xc = x0;
    for (int l = 0; l < NLAYERS; ++l) {
        k_agg<<<AB, 256, 0, stream>>>((const float4*)xc, offs, csr, (float4*)agg);
        k_mlp<<<1024, 256, 0, stream>>>(xc, agg,
                                        cW1 + (size_t)l * 64 * 64, cb1 + l * 64,
                                        cW2 + (size_t)l * 64 * 64, cb2 + l * 64,
                                        stats + l * 128);
        k_bn<<<AB, 256, 0, stream>>>((const float4*)agg, stats + l * 128,
                                     gam + l * 64, bet + l * 64, (float4*)xbuf);
        xc = xbuf;
    }

    k_pool<<<NGRAPH, 256, 0, stream>>>((const float4*)xc, bounds, (float4*)pooled);
    k_head<<<1, 128, 0, stream>>>(pooled, hW1, hb1, hW2, hb2, out);
}

// Round 3
// 1190.156 us; speedup vs baseline: 1.4039x; 1.0503x over previous
//
#include <hip/hip_runtime.h>

#define N_NODES 100000
#define N_EDGES 1600000
#define HDIM    64
#define NLAYERS 5
#define NGRAPH  128
#define NOUT    10
#define BN_EPS  1e-5f

// ---------------- CSR build ----------------

__global__ __launch_bounds__(256) void k_hist(const int* __restrict__ dst, int* __restrict__ counts) {
    int e = blockIdx.x * 256 + threadIdx.x;
    if (e < N_EDGES) atomicAdd(&counts[dst[e]], 1);
}

__global__ __launch_bounds__(256) void k_scan_bt(const int* __restrict__ counts, int* __restrict__ bsums) {
    __shared__ int sm[256];
    int t = threadIdx.x;
    int base = blockIdx.x * 1024 + t * 4;
    int s = 0;
#pragma unroll
    for (int k = 0; k < 4; ++k) { int i = base + k; s += (i < N_NODES) ? counts[i] : 0; }
    sm[t] = s; __syncthreads();
    for (int o = 128; o > 0; o >>= 1) { if (t < o) sm[t] += sm[t + o]; __syncthreads(); }
    if (t == 0) bsums[blockIdx.x] = sm[0];
}

__global__ void k_scan_tot(int* bsums, int nblk, int* offsets) {
    if (threadIdx.x == 0 && blockIdx.x == 0) {
        int run = 0;
        for (int i = 0; i < nblk; ++i) { int v = bsums[i]; bsums[i] = run; run += v; }
        offsets[N_NODES] = N_EDGES;
    }
}

__global__ __launch_bounds__(256) void k_scan_fin(const int* __restrict__ counts, const int* __restrict__ bsums,
                                                 int* __restrict__ offsets, int* __restrict__ cursor) {
    __shared__ int sm[256];
    int t = threadIdx.x;
    int base = blockIdx.x * 1024 + t * 4;
    int v[4]; int s = 0;
#pragma unroll
    for (int k = 0; k < 4; ++k) { int i = base + k; v[k] = (i < N_NODES) ? counts[i] : 0; s += v[k]; }
    sm[t] = s; __syncthreads();
    for (int o = 1; o < 256; o <<= 1) {
        int add = (t >= o) ? sm[t - o] : 0;
        __syncthreads();
        sm[t] += add;
        __syncthreads();
    }
    int run = bsums[blockIdx.x] + (sm[t] - s);
#pragma unroll
    for (int k = 0; k < 4; ++k) {
        int i = base + k;
        if (i < N_NODES) { offsets[i] = run; cursor[i] = run; run += v[k]; }
    }
}

__global__ __launch_bounds__(256) void k_fill(const int* __restrict__ src, const int* __restrict__ dst,
                                              int* __restrict__ cursor, int* __restrict__ csr) {
    int e = blockIdx.x * 256 + threadIdx.x;
    if (e < N_EDGES) {
        int d = dst[e];
        int p = atomicAdd(&cursor[d], 1);
        csr[p] = src[e];
    }
}

// ---------------- per-layer kernels ----------------

// 16 lanes per node, float4 per lane: agg[n] = sum over in-edges of x[src]
__global__ __launch_bounds__(256) void k_agg(const float4* __restrict__ x4, const int* __restrict__ offsets,
                                             const int* __restrict__ csr, float4* __restrict__ agg4) {
    int tid = blockIdx.x * 256 + threadIdx.x;
    int n = tid >> 4, q = tid & 15;
    if (n >= N_NODES) return;
    int beg = offsets[n], end = offsets[n + 1];
    float4 a = make_float4(0.f, 0.f, 0.f, 0.f);
    for (int e = beg; e < end; ++e) {
        int s = csr[e];
        float4 v = x4[s * 16 + q];
        a.x += v.x; a.y += v.y; a.z += v.z; a.w += v.w;
    }
    agg4[n * 16 + q] = a;
}

// thread = node. Input row staged in LDS (stride 68 floats: 16B-aligned rows,
// scalar reads only 8-way-conflicted and hidden under FMA). Weights read at
// wave-uniform addresses -> s_load stream; 64 independent FMA chains.
#define MLP_TB 128
#define ROWS   68
__global__ __launch_bounds__(MLP_TB) void k_mlp2(const float* __restrict__ x, float* __restrict__ aggh2,
                                                 const float* __restrict__ W1, const float* __restrict__ b1,
                                                 const float* __restrict__ W2, const float* __restrict__ b2) {
    __shared__ float sm[MLP_TB * ROWS];
    int t = threadIdx.x;
    int base = blockIdx.x * MLP_TB;
    // cooperative coalesced staging: inj = x + agg for this block's 128 rows
    for (int i = t; i < MLP_TB * 16; i += MLP_TB) {
        int r = i >> 4, q = i & 15;
        int n = base + r; if (n >= N_NODES) n = N_NODES - 1;
        float4 xv = ((const float4*)x)[(size_t)n * 16 + q];
        float4 av = ((const float4*)aggh2)[(size_t)n * 16 + q];
        float4 s; s.x = xv.x + av.x; s.y = xv.y + av.y; s.z = xv.z + av.z; s.w = xv.w + av.w;
        *((float4*)&sm[r * ROWS + q * 4]) = s;
    }
    __syncthreads();
    int n = base + t;
    bool valid = n < N_NODES;
    float* row = &sm[t * ROWS];
    float acc[64];
#pragma unroll
    for (int j = 0; j < 64; ++j) acc[j] = b1[j];
    for (int k = 0; k < 64; ++k) {
        float xk = row[k];
        const float* w = &W1[k * 64];
#pragma unroll
        for (int j = 0; j < 64; ++j) acc[j] = fmaf(xk, w[j], acc[j]);
    }
#pragma unroll
    for (int q = 0; q < 16; ++q) {
        float4 h;
        h.x = fmaxf(acc[4 * q + 0], 0.f);
        h.y = fmaxf(acc[4 * q + 1], 0.f);
        h.z = fmaxf(acc[4 * q + 2], 0.f);
        h.w = fmaxf(acc[4 * q + 3], 0.f);
        *((float4*)&row[q * 4]) = h;   // own row only: no barrier needed
    }
#pragma unroll
    for (int j = 0; j < 64; ++j) acc[j] = b2[j];
    for (int k = 0; k < 64; ++k) {
        float xk = row[k];
        const float* w = &W2[k * 64];
#pragma unroll
        for (int j = 0; j < 64; ++j) acc[j] = fmaf(xk, w[j], acc[j]);
    }
    if (valid) {
        float4* o = (float4*)(aggh2 + (size_t)n * 64);
#pragma unroll
        for (int q = 0; q < 16; ++q)
            o[q] = make_float4(acc[4 * q + 0], acc[4 * q + 1], acc[4 * q + 2], acc[4 * q + 3]);
    }
}

// per-feature sum/sumsq over nodes: lane = feature, few waves, 2 atomics/wave
__global__ __launch_bounds__(256) void k_stats(const float* __restrict__ h2, float* __restrict__ stats) {
    int lane = threadIdx.x & 63;
    int wave = (blockIdx.x * blockDim.x + threadIdx.x) >> 6;
    int nwaves = (gridDim.x * blockDim.x) >> 6;
    float lsum = 0.f, lsq = 0.f;
    for (int n = wave; n < N_NODES; n += nwaves) {
        float v = h2[(size_t)n * 64 + lane];
        lsum += v; lsq += v * v;
    }
    atomicAdd(&stats[lane], lsum);
    atomicAdd(&stats[64 + lane], lsq);
}

__global__ __launch_bounds__(256) void k_bn(const float4* __restrict__ h2, const float* __restrict__ stats,
                                            const float* __restrict__ gam, const float* __restrict__ bet,
                                            float4* __restrict__ xout) {
    int tid = blockIdx.x * 256 + threadIdx.x;
    if (tid >= N_NODES * 16) return;
    int j0 = (tid & 15) * 4;
    const float invN = 1.0f / (float)N_NODES;
    float sc[4], sh[4];
#pragma unroll
    for (int c = 0; c < 4; ++c) {
        int j = j0 + c;
        float mean = stats[j] * invN;
        float var = stats[64 + j] * invN - mean * mean;
        float s = gam[j] * rsqrtf(var + BN_EPS);
        sc[c] = s; sh[c] = bet[j] - mean * s;
    }
    float4 v = h2[tid];
    v.x = fmaxf(fmaf(v.x, sc[0], sh[0]), 0.f);
    v.y = fmaxf(fmaf(v.y, sc[1], sh[1]), 0.f);
    v.z = fmaxf(fmaf(v.z, sc[2], sh[2]), 0.f);
    v.w = fmaxf(fmaf(v.w, sc[3], sh[3]), 0.f);
    xout[tid] = v;
}

// ---------------- pooling + head (b is sorted -> segment boundaries) ----------------

__global__ void k_bounds(const int* __restrict__ b, int* __restrict__ bounds) {
    int g = threadIdx.x;           // 0..NGRAPH inclusive
    if (g > NGRAPH) return;
    int lo = 0, hi = N_NODES;      // first i with b[i] >= g
    while (lo < hi) { int mid = (lo + hi) >> 1; if (b[mid] < g) lo = mid + 1; else hi = mid; }
    bounds[g] = lo;
}

__global__ __launch_bounds__(256) void k_pool(const float4* __restrict__ x4, const int* __restrict__ bounds,
                                              float4* __restrict__ pooled4) {
    int g = blockIdx.x;
    int beg = bounds[g], end = bounds[g + 1];
    int t = threadIdx.x;
    int q = t & 15;
    int w = t >> 4;
    float4 a = make_float4(0.f, 0.f, 0.f, 0.f);
    for (int n = beg + w; n < end; n += 16) {
        float4 v = x4[n * 16 + q];
        a.x += v.x; a.y += v.y; a.z += v.z; a.w += v.w;
    }
    __shared__ float4 sm[16][16];
    sm[w][q] = a; __syncthreads();
    for (int o = 8; o > 0; o >>= 1) {
        if (w < o) {
            float4 u = sm[w + o][q];
            sm[w][q].x += u.x; sm[w][q].y += u.y; sm[w][q].z += u.z; sm[w][q].w += u.w;
        }
        __syncthreads();
    }
    if (w == 0) {
        float inv = (end > beg) ? 1.0f / (float)(end - beg) : 0.0f;
        float4 r = sm[0][q];
        r.x *= inv; r.y *= inv; r.z *= inv; r.w *= inv;
        pooled4[g * 16 + q] = r;
    }
}

__global__ __launch_bounds__(128) void k_head(const float* __restrict__ pooled,
                                              const float* __restrict__ W1, const float* __restrict__ b1,
                                              const float* __restrict__ W2, const float* __restrict__ b2,
                                              float* __restrict__ out) {
    __shared__ float w1s[64 * 64];
    __shared__ float w2s[64 * NOUT];
    int t = threadIdx.x;
    for (int i = t; i < 64 * 64; i += 128) w1s[i] = W1[i];
    for (int i = t; i < 64 * NOUT; i += 128) w2s[i] = W2[i];
    __syncthreads();
    int g = t;  // 128 threads == NGRAPH
    float pr[64];
#pragma unroll
    for (int k = 0; k < 64; ++k) pr[k] = pooled[g * 64 + k];
    float acc[NOUT];
#pragma unroll
    for (int o = 0; o < NOUT; ++o) acc[o] = b2[o];
    for (int j = 0; j < 64; ++j) {
        float h = b1[j];
#pragma unroll
        for (int k = 0; k < 64; ++k) h = fmaf(pr[k], w1s[k * 64 + j], h);
        h = fmaxf(h, 0.f);
#pragma unroll
        for (int o = 0; o < NOUT; ++o) acc[o] = fmaf(h, w2s[j * NOUT + o], acc[o]);
    }
#pragma unroll
    for (int o = 0; o < NOUT; ++o) out[g * NOUT + o] = acc[o];
}

// ---------------- launch ----------------

extern "C" void kernel_launch(void* const* d_in, const int* in_sizes, int n_in,
                              void* d_out, int out_size, void* d_ws, size_t ws_size,
                              hipStream_t stream) {
    const float* x0  = (const float*)d_in[0];
    const int*   ei  = (const int*)d_in[1];
    const int*   b   = (const int*)d_in[2];
    const float* cW1 = (const float*)d_in[3];
    const float* cb1 = (const float*)d_in[4];
    const float* cW2 = (const float*)d_in[5];
    const float* cb2 = (const float*)d_in[6];
    const float* gam = (const float*)d_in[7];
    const float* bet = (const float*)d_in[8];
    const float* hW1 = (const float*)d_in[9];
    const float* hb1 = (const float*)d_in[10];
    const float* hW2 = (const float*)d_in[11];
    const float* hb2 = (const float*)d_in[12];
    float* out = (float*)d_out;

    char* ws = (char*)d_ws;
    size_t off = 0;
    auto alloc = [&](size_t bytes) { void* p = ws + off; off += (bytes + 255) & ~(size_t)255; return p; };
    float* agg    = (float*)alloc((size_t)N_NODES * 64 * sizeof(float));   // doubles as h2
    float* xbuf   = (float*)alloc((size_t)N_NODES * 64 * sizeof(float));
    int*   csr    = (int*)alloc((size_t)N_EDGES * sizeof(int));
    int*   counts = (int*)alloc((size_t)(N_NODES + 1) * sizeof(int));
    int*   offs   = (int*)alloc((size_t)(N_NODES + 1) * sizeof(int));
    int*   cursor = (int*)alloc((size_t)(N_NODES + 1) * sizeof(int));
    int*   bsums  = (int*)alloc(256 * sizeof(int));
    float* stats  = (float*)alloc(NLAYERS * 128 * sizeof(float));
    float* pooled = (float*)alloc(NGRAPH * 64 * sizeof(float));
    int*   bounds = (int*)alloc((NGRAPH + 1) * sizeof(int));

    const int* src = ei;
    const int* dst = ei + N_EDGES;

    hipMemsetAsync(counts, 0, (N_NODES + 1) * sizeof(int), stream);
    hipMemsetAsync(stats, 0, NLAYERS * 128 * sizeof(float), stream);

    const int EB = (N_EDGES + 255) / 256;            // 6250
    const int SB = (N_NODES + 1023) / 1024;          // 98
    k_hist<<<EB, 256, 0, stream>>>(dst, counts);
    k_scan_bt<<<SB, 256, 0, stream>>>(counts, bsums);
    k_scan_tot<<<1, 1, 0, stream>>>(bsums, SB, offs);
    k_scan_fin<<<SB, 256, 0, stream>>>(counts, bsums, offs, cursor);
    k_fill<<<EB, 256, 0, stream>>>(src, dst, cursor, csr);
    k_bounds<<<1, NGRAPH + 1, 0, stream>>>(b, bounds);

    const int AB = (N_NODES * 16 + 255) / 256;       // 6250
    const int MB_G = (N_NODES + MLP_TB - 1) / MLP_TB; // 782
    const float* xc = x0;
    for (int l = 0; l < NLAYERS; ++l) {
        k_agg<<<AB, 256, 0, stream>>>((const float4*)xc, offs, csr, (float4*)agg);
        k_mlp2<<<MB_G, MLP_TB, 0, stream>>>(xc, agg,
                                            cW1 + (size_t)l * 64 * 64, cb1 + l * 64,
                                            cW2 + (size_t)l * 64 * 64, cb2 + l * 64);
        k_stats<<<512, 256, 0, stream>>>(agg, stats + l * 128);
        k_bn<<<AB, 256, 0, stream>>>((const float4*)agg, stats + l * 128,
                                     gam + l * 64, bet + l * 64, (float4*)xbuf);
        xc = xbuf;
    }

    k_pool<<<NGRAPH, 256, 0, stream>>>((const float4*)xc, bounds, (float4*)pooled);
    k_head<<<1, 128, 0, stream>>>(pooled, hW1, hb1, hW2, hb2, out);
}

// Round 4
// 892.965 us; speedup vs baseline: 1.8711x; 1.3328x over previous
//
#include <hip/hip_runtime.h>

#define N_NODES 100000
#define N_EDGES 1600000
#define HDIM    64
#define NLAYERS 5
#define NGRAPH  128
#define NOUT    10
#define BN_EPS  1e-5f

// ---------------- CSR build ----------------

__global__ __launch_bounds__(256) void k_hist(const int* __restrict__ dst, int* __restrict__ counts) {
    int e = blockIdx.x * 256 + threadIdx.x;
    if (e < N_EDGES) atomicAdd(&counts[dst[e]], 1);
}

__global__ __launch_bounds__(256) void k_scan_bt(const int* __restrict__ counts, int* __restrict__ bsums) {
    __shared__ int sm[256];
    int t = threadIdx.x;
    int base = blockIdx.x * 1024 + t * 4;
    int s = 0;
#pragma unroll
    for (int k = 0; k < 4; ++k) { int i = base + k; s += (i < N_NODES) ? counts[i] : 0; }
    sm[t] = s; __syncthreads();
    for (int o = 128; o > 0; o >>= 1) { if (t < o) sm[t] += sm[t + o]; __syncthreads(); }
    if (t == 0) bsums[blockIdx.x] = sm[0];
}

__global__ void k_scan_tot(int* bsums, int nblk, int* offsets) {
    if (threadIdx.x == 0 && blockIdx.x == 0) {
        int run = 0;
        for (int i = 0; i < nblk; ++i) { int v = bsums[i]; bsums[i] = run; run += v; }
        offsets[N_NODES] = N_EDGES;
    }
}

__global__ __launch_bounds__(256) void k_scan_fin(const int* __restrict__ counts, const int* __restrict__ bsums,
                                                 int* __restrict__ offsets, int* __restrict__ cursor) {
    __shared__ int sm[256];
    int t = threadIdx.x;
    int base = blockIdx.x * 1024 + t * 4;
    int v[4]; int s = 0;
#pragma unroll
    for (int k = 0; k < 4; ++k) { int i = base + k; v[k] = (i < N_NODES) ? counts[i] : 0; s += v[k]; }
    sm[t] = s; __syncthreads();
    for (int o = 1; o < 256; o <<= 1) {
        int add = (t >= o) ? sm[t - o] : 0;
        __syncthreads();
        sm[t] += add;
        __syncthreads();
    }
    int run = bsums[blockIdx.x] + (sm[t] - s);
#pragma unroll
    for (int k = 0; k < 4; ++k) {
        int i = base + k;
        if (i < N_NODES) { offsets[i] = run; cursor[i] = run; run += v[k]; }
    }
}

__global__ __launch_bounds__(256) void k_fill(const int* __restrict__ src, const int* __restrict__ dst,
                                              int* __restrict__ cursor, int* __restrict__ csr) {
    int e = blockIdx.x * 256 + threadIdx.x;
    if (e < N_EDGES) {
        int d = dst[e];
        int p = atomicAdd(&cursor[d], 1);
        csr[p] = src[e];
    }
}

// ---------------- per-layer kernels (BN fused into consumers) ----------------

// per-lane (4 features) BN scale/shift from raw stats
static __device__ __forceinline__ void bn_coeffs(const float* stats, const float* gam, const float* bet,
                                                 int j0, float4& sc, float4& sh) {
    const float invN = 1.0f / (float)N_NODES;
    float m, v, s;
    m = stats[j0+0]*invN; v = stats[64+j0+0]*invN - m*m; s = gam[j0+0]*rsqrtf(v+BN_EPS); sc.x = s; sh.x = bet[j0+0]-m*s;
    m = stats[j0+1]*invN; v = stats[64+j0+1]*invN - m*m; s = gam[j0+1]*rsqrtf(v+BN_EPS); sc.y = s; sh.y = bet[j0+1]-m*s;
    m = stats[j0+2]*invN; v = stats[64+j0+2]*invN - m*m; s = gam[j0+2]*rsqrtf(v+BN_EPS); sc.z = s; sh.z = bet[j0+2]-m*s;
    m = stats[j0+3]*invN; v = stats[64+j0+3]*invN - m*m; s = gam[j0+3]*rsqrtf(v+BN_EPS); sc.w = s; sh.w = bet[j0+3]-m*s;
}

static __device__ __forceinline__ float4 bn_apply(float4 v, const float4& sc, const float4& sh) {
    v.x = fmaxf(fmaf(v.x, sc.x, sh.x), 0.f);
    v.y = fmaxf(fmaf(v.y, sc.y, sh.y), 0.f);
    v.z = fmaxf(fmaf(v.z, sc.z, sh.z), 0.f);
    v.w = fmaxf(fmaf(v.w, sc.w, sh.w), 0.f);
    return v;
}

// 16 lanes per node, float4 per lane; gathers h2prev rows, applies prev-layer
// BN+ReLU on the fly (APPLY=false for layer 0 reading raw x0).
template <bool APPLY>
__global__ __launch_bounds__(256) void k_agg(const float4* __restrict__ x4, const int* __restrict__ offsets,
                                             const int* __restrict__ csr, float4* __restrict__ agg4,
                                             const float* __restrict__ stats, const float* __restrict__ gam,
                                             const float* __restrict__ bet) {
    int tid = blockIdx.x * 256 + threadIdx.x;
    int n = tid >> 4, q = tid & 15;
    if (n >= N_NODES) return;
    float4 sc, sh;
    if (APPLY) bn_coeffs(stats, gam, bet, q * 4, sc, sh);
    int beg = offsets[n], end = offsets[n + 1];
    float4 a0 = make_float4(0.f, 0.f, 0.f, 0.f);
    float4 a1 = make_float4(0.f, 0.f, 0.f, 0.f);
    int e = beg;
    for (; e + 1 < end; e += 2) {
        int s0 = csr[e], s1 = csr[e + 1];
        float4 v0 = x4[(size_t)s0 * 16 + q];
        float4 v1 = x4[(size_t)s1 * 16 + q];
        if (APPLY) { v0 = bn_apply(v0, sc, sh); v1 = bn_apply(v1, sc, sh); }
        a0.x += v0.x; a0.y += v0.y; a0.z += v0.z; a0.w += v0.w;
        a1.x += v1.x; a1.y += v1.y; a1.z += v1.z; a1.w += v1.w;
    }
    if (e < end) {
        int s0 = csr[e];
        float4 v0 = x4[(size_t)s0 * 16 + q];
        if (APPLY) v0 = bn_apply(v0, sc, sh);
        a0.x += v0.x; a0.y += v0.y; a0.z += v0.z; a0.w += v0.w;
    }
    a0.x += a1.x; a0.y += a1.y; a0.z += a1.z; a0.w += a1.w;
    agg4[(size_t)n * 16 + q] = a0;
}

// thread = node; input row = BN(h2prev) + agg staged in LDS; weights via
// wave-uniform s_load stream; 64 independent FMA chains. Writes h2 in-place
// over agg (own rows only) and accumulates BN stats for this layer.
#define MLP_TB 128
#define ROWS   68
template <bool APPLY>
__global__ __launch_bounds__(MLP_TB) void k_mlp2(const float* __restrict__ x, float* __restrict__ aggh2,
                                                 const float* __restrict__ W1, const float* __restrict__ b1,
                                                 const float* __restrict__ W2, const float* __restrict__ b2,
                                                 const float* __restrict__ statsPrev, const float* __restrict__ gam,
                                                 const float* __restrict__ bet, float* __restrict__ statsOut) {
    __shared__ float sm[MLP_TB * ROWS];
    __shared__ float red1[MLP_TB], red2[MLP_TB];
    int t = threadIdx.x;
    int base = blockIdx.x * MLP_TB;
    {
        int q = t & 15;                 // constant per thread across staging iters
        float4 sc, sh;
        if (APPLY) bn_coeffs(statsPrev, gam, bet, q * 4, sc, sh);
        for (int i = t; i < MLP_TB * 16; i += MLP_TB) {
            int r = i >> 4;
            int n = base + r; if (n >= N_NODES) n = N_NODES - 1;
            float4 xv = ((const float4*)x)[(size_t)n * 16 + q];
            if (APPLY) xv = bn_apply(xv, sc, sh);
            float4 av = ((const float4*)aggh2)[(size_t)n * 16 + q];
            float4 s; s.x = xv.x + av.x; s.y = xv.y + av.y; s.z = xv.z + av.z; s.w = xv.w + av.w;
            *((float4*)&sm[r * ROWS + q * 4]) = s;
        }
    }
    __syncthreads();
    int n = base + t;
    bool valid = n < N_NODES;
    float* row = &sm[t * ROWS];
    float acc[64];
#pragma unroll
    for (int j = 0; j < 64; ++j) acc[j] = b1[j];
    for (int k = 0; k < 64; ++k) {
        float xk = row[k];
        const float* w = &W1[k * 64];
#pragma unroll
        for (int j = 0; j < 64; ++j) acc[j] = fmaf(xk, w[j], acc[j]);
    }
#pragma unroll
    for (int q = 0; q < 16; ++q) {
        float4 h;
        h.x = fmaxf(acc[4 * q + 0], 0.f);
        h.y = fmaxf(acc[4 * q + 1], 0.f);
        h.z = fmaxf(acc[4 * q + 2], 0.f);
        h.w = fmaxf(acc[4 * q + 3], 0.f);
        *((float4*)&row[q * 4]) = h;   // own row only
    }
#pragma unroll
    for (int j = 0; j < 64; ++j) acc[j] = b2[j];
    for (int k = 0; k < 64; ++k) {
        float xk = row[k];
        const float* w = &W2[k * 64];
#pragma unroll
        for (int j = 0; j < 64; ++j) acc[j] = fmaf(xk, w[j], acc[j]);
    }
    if (valid) {
        float4* o = (float4*)(aggh2 + (size_t)n * 64);
#pragma unroll
        for (int q = 0; q < 16; ++q)
            o[q] = make_float4(acc[4 * q + 0], acc[4 * q + 1], acc[4 * q + 2], acc[4 * q + 3]);
    }
    // ---- fused BN statistics (zeros for padding rows keep sums exact) ----
#pragma unroll
    for (int q = 0; q < 16; ++q) {
        float4 h;
        if (valid) h = make_float4(acc[4*q+0], acc[4*q+1], acc[4*q+2], acc[4*q+3]);
        else       h = make_float4(0.f, 0.f, 0.f, 0.f);
        *((float4*)&row[q * 4]) = h;
    }
    __syncthreads();
    {
        int j = t & 63, half = t >> 6;
        float s = 0.f, sq = 0.f;
        const float* col = &sm[(half * 64) * ROWS + j];
#pragma unroll 8
        for (int r = 0; r < 64; ++r) { float v = col[r * ROWS]; s += v; sq += v * v; }
        red1[t] = s; red2[t] = sq;
    }
    __syncthreads();
    if (t < 64) {
        atomicAdd(&statsOut[t], red1[t] + red1[t + 64]);
    } else {
        int j = t - 64;
        atomicAdd(&statsOut[64 + j], red2[j] + red2[j + 64]);
    }
}

// ---------------- pooling + head (b is sorted -> segment boundaries) ----------------

__global__ void k_bounds(const int* __restrict__ b, int* __restrict__ bounds) {
    int g = threadIdx.x;
    if (g > NGRAPH) return;
    int lo = 0, hi = N_NODES;
    while (lo < hi) { int mid = (lo + hi) >> 1; if (b[mid] < g) lo = mid + 1; else hi = mid; }
    bounds[g] = lo;
}

// one block per graph; applies final-layer BN+ReLU on the fly
__global__ __launch_bounds__(256) void k_pool(const float4* __restrict__ x4, const int* __restrict__ bounds,
                                              float4* __restrict__ pooled4, const float* __restrict__ stats,
                                              const float* __restrict__ gam, const float* __restrict__ bet) {
    int g = blockIdx.x;
    int beg = bounds[g], end = bounds[g + 1];
    int t = threadIdx.x;
    int q = t & 15;
    int w = t >> 4;
    float4 sc, sh;
    bn_coeffs(stats, gam, bet, q * 4, sc, sh);
    float4 a = make_float4(0.f, 0.f, 0.f, 0.f);
    for (int n = beg + w; n < end; n += 16) {
        float4 v = bn_apply(x4[(size_t)n * 16 + q], sc, sh);
        a.x += v.x; a.y += v.y; a.z += v.z; a.w += v.w;
    }
    __shared__ float4 sm[16][16];
    sm[w][q] = a; __syncthreads();
    for (int o = 8; o > 0; o >>= 1) {
        if (w < o) {
            float4 u = sm[w + o][q];
            sm[w][q].x += u.x; sm[w][q].y += u.y; sm[w][q].z += u.z; sm[w][q].w += u.w;
        }
        __syncthreads();
    }
    if (w == 0) {
        float inv = (end > beg) ? 1.0f / (float)(end - beg) : 0.0f;
        float4 r = sm[0][q];
        r.x *= inv; r.y *= inv; r.z *= inv; r.w *= inv;
        pooled4[g * 16 + q] = r;
    }
}

__global__ __launch_bounds__(128) void k_head(const float* __restrict__ pooled,
                                              const float* __restrict__ W1, const float* __restrict__ b1,
                                              const float* __restrict__ W2, const float* __restrict__ b2,
                                              float* __restrict__ out) {
    __shared__ float w1s[64 * 64];
    __shared__ float w2s[64 * NOUT];
    int t = threadIdx.x;
    for (int i = t; i < 64 * 64; i += 128) w1s[i] = W1[i];
    for (int i = t; i < 64 * NOUT; i += 128) w2s[i] = W2[i];
    __syncthreads();
    int g = t;
    float pr[64];
#pragma unroll
    for (int k = 0; k < 64; ++k) pr[k] = pooled[g * 64 + k];
    float acc[NOUT];
#pragma unroll
    for (int o = 0; o < NOUT; ++o) acc[o] = b2[o];
    for (int j = 0; j < 64; ++j) {
        float h = b1[j];
#pragma unroll
        for (int k = 0; k < 64; ++k) h = fmaf(pr[k], w1s[k * 64 + j], h);
        h = fmaxf(h, 0.f);
#pragma unroll
        for (int o = 0; o < NOUT; ++o) acc[o] = fmaf(h, w2s[j * NOUT + o], acc[o]);
    }
#pragma unroll
    for (int o = 0; o < NOUT; ++o) out[g * NOUT + o] = acc[o];
}

// ---------------- launch ----------------

extern "C" void kernel_launch(void* const* d_in, const int* in_sizes, int n_in,
                              void* d_out, int out_size, void* d_ws, size_t ws_size,
                              hipStream_t stream) {
    const float* x0  = (const float*)d_in[0];
    const int*   ei  = (const int*)d_in[1];
    const int*   b   = (const int*)d_in[2];
    const float* cW1 = (const float*)d_in[3];
    const float* cb1 = (const float*)d_in[4];
    const float* cW2 = (const float*)d_in[5];
    const float* cb2 = (const float*)d_in[6];
    const float* gam = (const float*)d_in[7];
    const float* bet = (const float*)d_in[8];
    const float* hW1 = (const float*)d_in[9];
    const float* hb1 = (const float*)d_in[10];
    const float* hW2 = (const float*)d_in[11];
    const float* hb2 = (const float*)d_in[12];
    float* out = (float*)d_out;

    char* ws = (char*)d_ws;
    size_t off = 0;
    auto alloc = [&](size_t bytes) { void* p = ws + off; off += (bytes + 255) & ~(size_t)255; return p; };
    float* bufA   = (float*)alloc((size_t)N_NODES * 64 * sizeof(float));
    float* bufB   = (float*)alloc((size_t)N_NODES * 64 * sizeof(float));
    int*   csr    = (int*)alloc((size_t)N_EDGES * sizeof(int));
    int*   counts = (int*)alloc((size_t)(N_NODES + 1) * sizeof(int));
    int*   offs   = (int*)alloc((size_t)(N_NODES + 1) * sizeof(int));
    int*   cursor = (int*)alloc((size_t)(N_NODES + 1) * sizeof(int));
    int*   bsums  = (int*)alloc(256 * sizeof(int));
    float* stats  = (float*)alloc(NLAYERS * 128 * sizeof(float));
    float* pooled = (float*)alloc(NGRAPH * 64 * sizeof(float));
    int*   bounds = (int*)alloc((NGRAPH + 1) * sizeof(int));

    const int* src = ei;
    const int* dst = ei + N_EDGES;

    hipMemsetAsync(counts, 0, (N_NODES + 1) * sizeof(int), stream);
    hipMemsetAsync(stats, 0, NLAYERS * 128 * sizeof(float), stream);

    const int EB = (N_EDGES + 255) / 256;
    const int SB = (N_NODES + 1023) / 1024;
    k_hist<<<EB, 256, 0, stream>>>(dst, counts);
    k_scan_bt<<<SB, 256, 0, stream>>>(counts, bsums);
    k_scan_tot<<<1, 1, 0, stream>>>(bsums, SB, offs);
    k_scan_fin<<<SB, 256, 0, stream>>>(counts, bsums, offs, cursor);
    k_fill<<<EB, 256, 0, stream>>>(src, dst, cursor, csr);
    k_bounds<<<1, NGRAPH + 1, 0, stream>>>(b, bounds);

    const int AB = (N_NODES * 16 + 255) / 256;
    const int MB_G = (N_NODES + MLP_TB - 1) / MLP_TB;

    const float* P = x0;      // h2prev (raw x for layer 0)
    float* Q = bufA;          // agg, then h2 of this layer (in-place)
    float* spare = bufB;
    for (int l = 0; l < NLAYERS; ++l) {
        const float* sPrev = stats + (size_t)(l - 1) * 128;
        const float* gPrev = gam + (size_t)(l - 1) * 64;
        const float* bPrev = bet + (size_t)(l - 1) * 64;
        if (l == 0) {
            k_agg<false><<<AB, 256, 0, stream>>>((const float4*)P, offs, csr, (float4*)Q,
                                                 nullptr, nullptr, nullptr);
            k_mlp2<false><<<MB_G, MLP_TB, 0, stream>>>(P, Q,
                                                       cW1, cb1, cW2, cb2,
                                                       nullptr, nullptr, nullptr, stats);
        } else {
            k_agg<true><<<AB, 256, 0, stream>>>((const float4*)P, offs, csr, (float4*)Q,
                                                sPrev, gPrev, bPrev);
            k_mlp2<true><<<MB_G, MLP_TB, 0, stream>>>(P, Q,
                                                      cW1 + (size_t)l * 64 * 64, cb1 + l * 64,
                                                      cW2 + (size_t)l * 64 * 64, cb2 + l * 64,
                                                      sPrev, gPrev, bPrev, stats + (size_t)l * 128);
        }
        // rotate: Q holds h2[l]; old P (if a ws buffer) becomes scratch
        float* newSpare = (P == x0) ? spare : (float*)P;
        P = Q;
        Q = newSpare;
        spare = nullptr; // only meaningful on first iteration
    }

    k_pool<<<NGRAPH, 256, 0, stream>>>((const float4*)P, bounds, (float4*)pooled,
                                       stats + 4 * 128, gam + 4 * 64, bet + 4 * 64);
    k_head<<<1, 128, 0, stream>>>(pooled, hW1, hb1, hW2, hb2, out);
}

// Round 5
// 830.207 us; speedup vs baseline: 2.0125x; 1.0756x over previous
//
#include <hip/hip_runtime.h>

#define N_NODES 100000
#define N_EDGES 1600000
#define HDIM    64
#define NLAYERS 5
#define NGRAPH  128
#define NOUT    10
#define BN_EPS  1e-5f
#define NBUCK   196          // ceil(N_NODES / 512)
#define EPB     8192         // edges per binfill block

// ---------------- CSR build ----------------

__global__ __launch_bounds__(256) void k_hist(const int* __restrict__ dst, int* __restrict__ counts) {
    int e = blockIdx.x * 256 + threadIdx.x;
    if (e < N_EDGES) atomicAdd(&counts[dst[e]], 1);
}

__global__ __launch_bounds__(256) void k_scan_bt(const int* __restrict__ counts, int* __restrict__ bsums) {
    __shared__ int sm[256];
    int t = threadIdx.x;
    int base = blockIdx.x * 1024 + t * 4;
    int s = 0;
#pragma unroll
    for (int k = 0; k < 4; ++k) { int i = base + k; s += (i < N_NODES) ? counts[i] : 0; }
    sm[t] = s; __syncthreads();
    for (int o = 128; o > 0; o >>= 1) { if (t < o) sm[t] += sm[t + o]; __syncthreads(); }
    if (t == 0) bsums[blockIdx.x] = sm[0];
}

__global__ void k_scan_tot(int* bsums, int nblk, int* offsets) {
    if (threadIdx.x == 0 && blockIdx.x == 0) {
        int run = 0;
        for (int i = 0; i < nblk; ++i) { int v = bsums[i]; bsums[i] = run; run += v; }
        offsets[N_NODES] = N_EDGES;
    }
}

__global__ __launch_bounds__(256) void k_scan_fin(const int* __restrict__ counts, const int* __restrict__ bsums,
                                                 int* __restrict__ offsets, int* __restrict__ cursor) {
    __shared__ int sm[256];
    int t = threadIdx.x;
    int base = blockIdx.x * 1024 + t * 4;
    int v[4]; int s = 0;
#pragma unroll
    for (int k = 0; k < 4; ++k) { int i = base + k; v[k] = (i < N_NODES) ? counts[i] : 0; s += v[k]; }
    sm[t] = s; __syncthreads();
    for (int o = 1; o < 256; o <<= 1) {
        int add = (t >= o) ? sm[t - o] : 0;
        __syncthreads();
        sm[t] += add;
        __syncthreads();
    }
    int run = bsums[blockIdx.x] + (sm[t] - s);
#pragma unroll
    for (int k = 0; k < 4; ++k) {
        int i = base + k;
        if (i < N_NODES) { offsets[i] = run; cursor[i] = run; run += v[k]; }
    }
}

__global__ void k_binit(const int* __restrict__ offs, int* __restrict__ bcursor) {
    int b = blockIdx.x * 256 + threadIdx.x;
    if (b < NBUCK) bcursor[b] = offs[b << 9];
}

// Bin edges by dst>>9 in LDS; write each bucket's edges as contiguous chunks
// into bucket-ordered tmp (packed: (dst&511)<<17 | src).
__global__ __launch_bounds__(1024) void k_binfill(const int* __restrict__ src, const int* __restrict__ dst,
                                                  int* __restrict__ bcursor, unsigned* __restrict__ tmp) {
    __shared__ unsigned slots[EPB];
    __shared__ int cnt[NBUCK], lcur[NBUCK], gbase[NBUCK];
    __shared__ int lbase[NBUCK + 1];
    __shared__ int sscan[256];
    int t = threadIdx.x;
    int e0 = blockIdx.x * EPB;
    for (int i = t; i < NBUCK; i += 1024) { cnt[i] = 0; lcur[i] = 0; }
    __syncthreads();
    unsigned pk[8]; int bk[8];
#pragma unroll
    for (int k = 0; k < 8; ++k) {
        int e = e0 + k * 1024 + t;
        bk[k] = -1;
        if (e < N_EDGES) {
            int s = src[e], d = dst[e];
            int b = d >> 9;
            pk[k] = ((unsigned)(d & 511) << 17) | (unsigned)s;
            bk[k] = b;
            atomicAdd(&cnt[b], 1);
        }
    }
    __syncthreads();
    if (t < 256) sscan[t] = (t < NBUCK) ? cnt[t] : 0;
    __syncthreads();
    for (int o = 1; o < 256; o <<= 1) {
        int v = 0;
        if (t < 256 && t >= o) v = sscan[t - o];
        __syncthreads();
        if (t < 256) sscan[t] += v;
        __syncthreads();
    }
    if (t < NBUCK) {
        lbase[t] = sscan[t] - cnt[t];
        gbase[t] = atomicAdd(&bcursor[t], cnt[t]);
    }
    if (t == 0) lbase[NBUCK] = sscan[255];
    __syncthreads();
#pragma unroll
    for (int k = 0; k < 8; ++k) {
        if (bk[k] >= 0) {
            int pos = lbase[bk[k]] + atomicAdd(&lcur[bk[k]], 1);
            slots[pos] = pk[k];
        }
    }
    __syncthreads();
    int total = lbase[NBUCK];
    for (int i = t; i < total; i += 1024) {
        int lo = 0, hi = NBUCK - 1;
        while (lo < hi) { int mid = (lo + hi + 1) >> 1; if (lbase[mid] <= i) lo = mid; else hi = mid - 1; }
        tmp[gbase[lo] + (i - lbase[lo])] = slots[i];
    }
}

// One block per bucket: scatter src into the bucket's csr region (33 KB,
// single-XCD resident -> L2 merges the 4B writes).
__global__ __launch_bounds__(1024) void k_localcsr(const unsigned* __restrict__ tmp, const int* __restrict__ offs,
                                                   int* __restrict__ cursor, int* __restrict__ csr) {
    int b = blockIdx.x;
    int nlo = b << 9;
    int nhi = nlo + 512; if (nhi > N_NODES) nhi = N_NODES;
    int base = offs[nlo], end = offs[nhi];
    for (int i = base + (int)threadIdx.x; i < end; i += 1024) {
        unsigned pk = tmp[i];
        int node = nlo + (int)(pk >> 17);
        int p = atomicAdd(&cursor[node], 1);
        csr[p] = (int)(pk & 0x1FFFFu);
    }
}

// ---------------- per-layer kernels (BN fused into consumers) ----------------

static __device__ __forceinline__ void bn_coeffs(const float* stats, const float* gam, const float* bet,
                                                 int j0, float4& sc, float4& sh) {
    const float invN = 1.0f / (float)N_NODES;
    float m, v, s;
    m = stats[j0+0]*invN; v = stats[64+j0+0]*invN - m*m; s = gam[j0+0]*rsqrtf(v+BN_EPS); sc.x = s; sh.x = bet[j0+0]-m*s;
    m = stats[j0+1]*invN; v = stats[64+j0+1]*invN - m*m; s = gam[j0+1]*rsqrtf(v+BN_EPS); sc.y = s; sh.y = bet[j0+1]-m*s;
    m = stats[j0+2]*invN; v = stats[64+j0+2]*invN - m*m; s = gam[j0+2]*rsqrtf(v+BN_EPS); sc.z = s; sh.z = bet[j0+2]-m*s;
    m = stats[j0+3]*invN; v = stats[64+j0+3]*invN - m*m; s = gam[j0+3]*rsqrtf(v+BN_EPS); sc.w = s; sh.w = bet[j0+3]-m*s;
}

static __device__ __forceinline__ float4 bn_apply(float4 v, const float4& sc, const float4& sh) {
    v.x = fmaxf(fmaf(v.x, sc.x, sh.x), 0.f);
    v.y = fmaxf(fmaf(v.y, sc.y, sh.y), 0.f);
    v.z = fmaxf(fmaf(v.z, sc.z, sh.z), 0.f);
    v.w = fmaxf(fmaf(v.w, sc.w, sh.w), 0.f);
    return v;
}

template <bool APPLY>
__global__ __launch_bounds__(256) void k_agg(const float4* __restrict__ x4, const int* __restrict__ offsets,
                                             const int* __restrict__ csr, float4* __restrict__ agg4,
                                             const float* __restrict__ stats, const float* __restrict__ gam,
                                             const float* __restrict__ bet) {
    int tid = blockIdx.x * 256 + threadIdx.x;
    int n = tid >> 4, q = tid & 15;
    if (n >= N_NODES) return;
    float4 sc, sh;
    if (APPLY) bn_coeffs(stats, gam, bet, q * 4, sc, sh);
    int beg = offsets[n], end = offsets[n + 1];
    float4 a0 = make_float4(0.f, 0.f, 0.f, 0.f);
    float4 a1 = make_float4(0.f, 0.f, 0.f, 0.f);
    int e = beg;
    for (; e + 1 < end; e += 2) {
        int s0 = csr[e], s1 = csr[e + 1];
        float4 v0 = x4[(size_t)s0 * 16 + q];
        float4 v1 = x4[(size_t)s1 * 16 + q];
        if (APPLY) { v0 = bn_apply(v0, sc, sh); v1 = bn_apply(v1, sc, sh); }
        a0.x += v0.x; a0.y += v0.y; a0.z += v0.z; a0.w += v0.w;
        a1.x += v1.x; a1.y += v1.y; a1.z += v1.z; a1.w += v1.w;
    }
    if (e < end) {
        int s0 = csr[e];
        float4 v0 = x4[(size_t)s0 * 16 + q];
        if (APPLY) v0 = bn_apply(v0, sc, sh);
        a0.x += v0.x; a0.y += v0.y; a0.z += v0.z; a0.w += v0.w;
    }
    a0.x += a1.x; a0.y += a1.y; a0.z += a1.z; a0.w += a1.w;
    agg4[(size_t)n * 16 + q] = a0;
}

#define MLP_TB 128
#define ROWS   68
template <bool APPLY>
__global__ __launch_bounds__(MLP_TB) void k_mlp2(const float* __restrict__ x, float* __restrict__ aggh2,
                                                 const float* __restrict__ W1, const float* __restrict__ b1,
                                                 const float* __restrict__ W2, const float* __restrict__ b2,
                                                 const float* __restrict__ statsPrev, const float* __restrict__ gam,
                                                 const float* __restrict__ bet, float* __restrict__ statsOut) {
    __shared__ float sm[MLP_TB * ROWS];
    __shared__ float red1[MLP_TB], red2[MLP_TB];
    int t = threadIdx.x;
    int base = blockIdx.x * MLP_TB;
    {
        int q = t & 15;
        float4 sc, sh;
        if (APPLY) bn_coeffs(statsPrev, gam, bet, q * 4, sc, sh);
        for (int i = t; i < MLP_TB * 16; i += MLP_TB) {
            int r = i >> 4;
            int n = base + r; if (n >= N_NODES) n = N_NODES - 1;
            float4 xv = ((const float4*)x)[(size_t)n * 16 + q];
            if (APPLY) xv = bn_apply(xv, sc, sh);
            float4 av = ((const float4*)aggh2)[(size_t)n * 16 + q];
            float4 s; s.x = xv.x + av.x; s.y = xv.y + av.y; s.z = xv.z + av.z; s.w = xv.w + av.w;
            *((float4*)&sm[r * ROWS + q * 4]) = s;
        }
    }
    __syncthreads();
    int n = base + t;
    bool valid = n < N_NODES;
    float* row = &sm[t * ROWS];
    float acc[64];
#pragma unroll
    for (int j = 0; j < 64; ++j) acc[j] = b1[j];
    for (int k = 0; k < 64; ++k) {
        float xk = row[k];
        const float* w = &W1[k * 64];
#pragma unroll
        for (int j = 0; j < 64; ++j) acc[j] = fmaf(xk, w[j], acc[j]);
    }
#pragma unroll
    for (int q = 0; q < 16; ++q) {
        float4 h;
        h.x = fmaxf(acc[4 * q + 0], 0.f);
        h.y = fmaxf(acc[4 * q + 1], 0.f);
        h.z = fmaxf(acc[4 * q + 2], 0.f);
        h.w = fmaxf(acc[4 * q + 3], 0.f);
        *((float4*)&row[q * 4]) = h;
    }
#pragma unroll
    for (int j = 0; j < 64; ++j) acc[j] = b2[j];
    for (int k = 0; k < 64; ++k) {
        float xk = row[k];
        const float* w = &W2[k * 64];
#pragma unroll
        for (int j = 0; j < 64; ++j) acc[j] = fmaf(xk, w[j], acc[j]);
    }
    if (valid) {
        float4* o = (float4*)(aggh2 + (size_t)n * 64);
#pragma unroll
        for (int q = 0; q < 16; ++q)
            o[q] = make_float4(acc[4 * q + 0], acc[4 * q + 1], acc[4 * q + 2], acc[4 * q + 3]);
    }
#pragma unroll
    for (int q = 0; q < 16; ++q) {
        float4 h;
        if (valid) h = make_float4(acc[4*q+0], acc[4*q+1], acc[4*q+2], acc[4*q+3]);
        else       h = make_float4(0.f, 0.f, 0.f, 0.f);
        *((float4*)&row[q * 4]) = h;
    }
    __syncthreads();
    {
        int j = t & 63, half = t >> 6;
        float s = 0.f, sq = 0.f;
        const float* col = &sm[(half * 64) * ROWS + j];
#pragma unroll 8
        for (int r = 0; r < 64; ++r) { float v = col[r * ROWS]; s += v; sq += v * v; }
        red1[t] = s; red2[t] = sq;
    }
    __syncthreads();
    if (t < 64) {
        atomicAdd(&statsOut[t], red1[t] + red1[t + 64]);
    } else {
        int j = t - 64;
        atomicAdd(&statsOut[64 + j], red2[j] + red2[j + 64]);
    }
}

// ---------------- pooling + head ----------------

__global__ void k_bounds(const int* __restrict__ b, int* __restrict__ bounds) {
    int g = threadIdx.x;
    if (g > NGRAPH) return;
    int lo = 0, hi = N_NODES;
    while (lo < hi) { int mid = (lo + hi) >> 1; if (b[mid] < g) lo = mid + 1; else hi = mid; }
    bounds[g] = lo;
}

__global__ __launch_bounds__(256) void k_pool(const float4* __restrict__ x4, const int* __restrict__ bounds,
                                              float4* __restrict__ pooled4, const float* __restrict__ stats,
                                              const float* __restrict__ gam, const float* __restrict__ bet) {
    int g = blockIdx.x;
    int beg = bounds[g], end = bounds[g + 1];
    int t = threadIdx.x;
    int q = t & 15;
    int w = t >> 4;
    float4 sc, sh;
    bn_coeffs(stats, gam, bet, q * 4, sc, sh);
    float4 a = make_float4(0.f, 0.f, 0.f, 0.f);
    for (int n = beg + w; n < end; n += 16) {
        float4 v = bn_apply(x4[(size_t)n * 16 + q], sc, sh);
        a.x += v.x; a.y += v.y; a.z += v.z; a.w += v.w;
    }
    __shared__ float4 sm[16][16];
    sm[w][q] = a; __syncthreads();
    for (int o = 8; o > 0; o >>= 1) {
        if (w < o) {
            float4 u = sm[w + o][q];
            sm[w][q].x += u.x; sm[w][q].y += u.y; sm[w][q].z += u.z; sm[w][q].w += u.w;
        }
        __syncthreads();
    }
    if (w == 0) {
        float inv = (end > beg) ? 1.0f / (float)(end - beg) : 0.0f;
        float4 r = sm[0][q];
        r.x *= inv; r.y *= inv; r.z *= inv; r.w *= inv;
        pooled4[g * 16 + q] = r;
    }
}

__global__ __launch_bounds__(128) void k_head(const float* __restrict__ pooled,
                                              const float* __restrict__ W1, const float* __restrict__ b1,
                                              const float* __restrict__ W2, const float* __restrict__ b2,
                                              float* __restrict__ out) {
    __shared__ float w1s[64 * 64];
    __shared__ float w2s[64 * NOUT];
    int t = threadIdx.x;
    for (int i = t; i < 64 * 64; i += 128) w1s[i] = W1[i];
    for (int i = t; i < 64 * NOUT; i += 128) w2s[i] = W2[i];
    __syncthreads();
    int g = t;
    float pr[64];
#pragma unroll
    for (int k = 0; k < 64; ++k) pr[k] = pooled[g * 64 + k];
    float acc[NOUT];
#pragma unroll
    for (int o = 0; o < NOUT; ++o) acc[o] = b2[o];
    for (int j = 0; j < 64; ++j) {
        float h = b1[j];
#pragma unroll
        for (int k = 0; k < 64; ++k) h = fmaf(pr[k], w1s[k * 64 + j], h);
        h = fmaxf(h, 0.f);
#pragma unroll
        for (int o = 0; o < NOUT; ++o) acc[o] = fmaf(h, w2s[j * NOUT + o], acc[o]);
    }
#pragma unroll
    for (int o = 0; o < NOUT; ++o) out[g * NOUT + o] = acc[o];
}

// ---------------- launch ----------------

extern "C" void kernel_launch(void* const* d_in, const int* in_sizes, int n_in,
                              void* d_out, int out_size, void* d_ws, size_t ws_size,
                              hipStream_t stream) {
    const float* x0  = (const float*)d_in[0];
    const int*   ei  = (const int*)d_in[1];
    const int*   b   = (const int*)d_in[2];
    const float* cW1 = (const float*)d_in[3];
    const float* cb1 = (const float*)d_in[4];
    const float* cW2 = (const float*)d_in[5];
    const float* cb2 = (const float*)d_in[6];
    const float* gam = (const float*)d_in[7];
    const float* bet = (const float*)d_in[8];
    const float* hW1 = (const float*)d_in[9];
    const float* hb1 = (const float*)d_in[10];
    const float* hW2 = (const float*)d_in[11];
    const float* hb2 = (const float*)d_in[12];
    float* out = (float*)d_out;

    char* ws = (char*)d_ws;
    size_t off = 0;
    auto alloc = [&](size_t bytes) { void* p = ws + off; off += (bytes + 255) & ~(size_t)255; return p; };
    float* bufA   = (float*)alloc((size_t)N_NODES * 64 * sizeof(float));
    float* bufB   = (float*)alloc((size_t)N_NODES * 64 * sizeof(float));
    int*   csr    = (int*)alloc((size_t)N_EDGES * sizeof(int));
    int*   counts = (int*)alloc((size_t)(N_NODES + 1) * sizeof(int));
    int*   offs   = (int*)alloc((size_t)(N_NODES + 1) * sizeof(int));
    int*   cursor = (int*)alloc((size_t)(N_NODES + 1) * sizeof(int));
    int*   bsums  = (int*)alloc(256 * sizeof(int));
    int*   bcursor= (int*)alloc(256 * sizeof(int));
    float* stats  = (float*)alloc(NLAYERS * 128 * sizeof(float));
    float* pooled = (float*)alloc(NGRAPH * 64 * sizeof(float));
    int*   bounds = (int*)alloc((NGRAPH + 1) * sizeof(int));
    unsigned* tmp = (unsigned*)bufB;   // alias: bufB unused until layer 1

    const int* src = ei;
    const int* dst = ei + N_EDGES;

    hipMemsetAsync(counts, 0, (N_NODES + 1) * sizeof(int), stream);
    hipMemsetAsync(stats, 0, NLAYERS * 128 * sizeof(float), stream);

    const int EB = (N_EDGES + 255) / 256;
    const int SB = (N_NODES + 1023) / 1024;
    const int FB = (N_EDGES + EPB - 1) / EPB;   // 196
    k_hist<<<EB, 256, 0, stream>>>(dst, counts);
    k_scan_bt<<<SB, 256, 0, stream>>>(counts, bsums);
    k_scan_tot<<<1, 1, 0, stream>>>(bsums, SB, offs);
    k_scan_fin<<<SB, 256, 0, stream>>>(counts, bsums, offs, cursor);
    k_binit<<<1, 256, 0, stream>>>(offs, bcursor);
    k_binfill<<<FB, 1024, 0, stream>>>(src, dst, bcursor, tmp);
    k_localcsr<<<NBUCK, 1024, 0, stream>>>(tmp, offs, cursor, csr);
    k_bounds<<<1, NGRAPH + 1, 0, stream>>>(b, bounds);

    const int AB = (N_NODES * 16 + 255) / 256;
    const int MB_G = (N_NODES + MLP_TB - 1) / MLP_TB;

    const float* P = x0;
    float* Q = bufA;
    float* spare = bufB;
    for (int l = 0; l < NLAYERS; ++l) {
        const float* sPrev = stats + (size_t)(l - 1) * 128;
        const float* gPrev = gam + (size_t)(l - 1) * 64;
        const float* bPrev = bet + (size_t)(l - 1) * 64;
        if (l == 0) {
            k_agg<false><<<AB, 256, 0, stream>>>((const float4*)P, offs, csr, (float4*)Q,
                                                 nullptr, nullptr, nullptr);
            k_mlp2<false><<<MB_G, MLP_TB, 0, stream>>>(P, Q,
                                                       cW1, cb1, cW2, cb2,
                                                       nullptr, nullptr, nullptr, stats);
        } else {
            k_agg<true><<<AB, 256, 0, stream>>>((const float4*)P, offs, csr, (float4*)Q,
                                                sPrev, gPrev, bPrev);
            k_mlp2<true><<<MB_G, MLP_TB, 0, stream>>>(P, Q,
                                                      cW1 + (size_t)l * 64 * 64, cb1 + l * 64,
                                                      cW2 + (size_t)l * 64 * 64, cb2 + l * 64,
                                                      sPrev, gPrev, bPrev, stats + (size_t)l * 128);
        }
        float* newSpare = (P == x0) ? spare : (float*)P;
        P = Q;
        Q = newSpare;
    }

    k_pool<<<NGRAPH, 256, 0, stream>>>((const float4*)P, bounds, (float4*)pooled,
                                       stats + 4 * 128, gam + 4 * 64, bet + 4 * 64);
    k_head<<<1, 128, 0, stream>>>(pooled, hW1, hb1, hW2, hb2, out);
}